// Round 7
// baseline (406.267 us; speedup 1.0000x reference)
//
#include <hip/hip_runtime.h>
#include <cfloat>

#define BB   32
#define VV   2048
#define KNB  40
#define FIN  64
#define DD   4
#define PP   64
#define NN   (BB*VV)           // 65536

static __device__ __forceinline__ float fast_tanh(float z) {
    z = fminf(fmaxf(z, -15.f), 15.f);
    float e = __expf(2.f * z);
    return (e - 1.f) / (e + 1.f);
}

// Wave64 inclusive add-scan via DPP (rocPRIM pattern): 6 VALU ops, no DS pipe.
static __device__ __forceinline__ int wave_incl_scan(int x) {
    x += __builtin_amdgcn_update_dpp(0, x, 0x111, 0xf, 0xf, true); // row_shr:1
    x += __builtin_amdgcn_update_dpp(0, x, 0x112, 0xf, 0xf, true); // row_shr:2
    x += __builtin_amdgcn_update_dpp(0, x, 0x114, 0xf, 0xf, true); // row_shr:4
    x += __builtin_amdgcn_update_dpp(0, x, 0x118, 0xf, 0xf, true); // row_shr:8
    x += __builtin_amdgcn_update_dpp(0, x, 0x142, 0xa, 0xf, true); // row_bcast:15 -> rows 1,3
    x += __builtin_amdgcn_update_dpp(0, x, 0x143, 0xc, 0xf, true); // row_bcast:31 -> rows 2,3
    return x;
}

// ---------------------------------------------------------------------------
// Kernel 1: coords = x@W_s + b_s (N x 4), feats = x@W_f + b_f (N x 64)
// (unchanged, passing)
// ---------------------------------------------------------------------------
__global__ __launch_bounds__(256) void k_embed(
    const float* __restrict__ x, const float* __restrict__ Ws,
    const float* __restrict__ bs, const float* __restrict__ Wf,
    const float* __restrict__ bf, float* __restrict__ coords,
    float* __restrict__ feats)
{
    __shared__ float Xs[64][68];
    __shared__ float Wfs[64][64];
    __shared__ float Wss[64][4];
    const int tid  = threadIdx.x;
    const int row0 = blockIdx.x * 64;

    #pragma unroll
    for (int i = 0; i < 4; ++i) {
        const int idx = tid + i * 256;
        const int r   = idx >> 4;
        const int k4  = (idx & 15) << 2;
        float4 v = *(const float4*)(x + (size_t)(row0 + r) * FIN + k4);
        Xs[k4+0][r] = v.x; Xs[k4+1][r] = v.y; Xs[k4+2][r] = v.z; Xs[k4+3][r] = v.w;
        ((float4*)Wfs)[idx] = ((const float4*)Wf)[idx];
    }
    if (tid < 64) *(float4*)Wss[tid] = ((const float4*)Ws)[tid];
    __syncthreads();

    const int tx = tid & 15;
    const int ty = tid >> 4;
    float acc[4][4] = {};
    #pragma unroll 16
    for (int k = 0; k < 64; ++k) {
        float4 a = *(const float4*)&Xs[k][ty * 4];
        float4 b = *(const float4*)&Wfs[k][tx * 4];
        acc[0][0] += a.x*b.x; acc[0][1] += a.x*b.y; acc[0][2] += a.x*b.z; acc[0][3] += a.x*b.w;
        acc[1][0] += a.y*b.x; acc[1][1] += a.y*b.y; acc[1][2] += a.y*b.z; acc[1][3] += a.y*b.w;
        acc[2][0] += a.z*b.x; acc[2][1] += a.z*b.y; acc[2][2] += a.z*b.z; acc[2][3] += a.z*b.w;
        acc[3][0] += a.w*b.x; acc[3][1] += a.w*b.y; acc[3][2] += a.w*b.z; acc[3][3] += a.w*b.w;
    }
    const float4 bfv = *(const float4*)(bf + tx * 4);
    const float ar[4] = {bfv.x, bfv.y, bfv.z, bfv.w};
    #pragma unroll
    for (int i = 0; i < 4; ++i) {
        float4 o = { acc[i][0] + ar[0], acc[i][1] + ar[1],
                     acc[i][2] + ar[2], acc[i][3] + ar[3] };
        *(float4*)(feats + (size_t)(row0 + ty * 4 + i) * PP + tx * 4) = o;
    }

    const int cr = tid >> 2, cc = tid & 3;
    float ca = bs[cc];
    #pragma unroll 16
    for (int k = 0; k < 64; ++k) ca += Xs[k][cr] * Wss[k][cc];
    coords[(size_t)(row0 + cr) * DD + cc] = ca;
}

// ---------------------------------------------------------------------------
// select_collect: given packed 8-bit bins (4/u32), nearmask (bit j: candidate
// was histogrammed), and the filled per-wave histogram, find the rank-40
// boundary and scatter the selected indices to cp[0..KNB).
// EXACTLY equivalent to the float-compare select of R4-R6:
//   bin < g1      <=>  d2 < g1/scale    (exact pow2 scale)
//   bin == g1 & near <=> d2 in boundary bin (far/self have near=0, matching
//   the old "FLT_MAX / d2>=hi fails both compares" exclusion).
// Returns false (before collecting) if total < KNB and allow_fail.
// ---------------------------------------------------------------------------
static __device__ __forceinline__ bool select_collect(
    const unsigned int (&bp)[8], const unsigned int nearmask,
    int* __restrict__ hw, int* __restrict__ cp, const int lane,
    const bool allow_fail)
{
    int4 hv = ((const int4*)hw)[lane];
    const int local = hv.x + hv.y + hv.z + hv.w;
    const int incl  = wave_incl_scan(local);
    if (allow_fail) {
        const int total = __builtin_amdgcn_readlane(incl, 63);
        if (total < KNB) return false;
    }
    const int excl = incl - local;
    const bool pred = (excl < KNB) && (incl >= KNB);
    const unsigned long long m = __ballot(pred);
    const int src = (m == 0ull) ? 0 : ((int)__ffsll(m) - 1);  // uniform
    int gg = 0, nnb = 0;
    if (pred) {
        const int hh[4] = {hv.x, hv.y, hv.z, hv.w};
        int cacc = excl, found = -1;
        #pragma unroll
        for (int q = 0; q < 4; ++q) {
            if (found < 0 && cacc + hh[q] >= KNB) { found = q; nnb = cacc; }
            cacc += hh[q];
        }
        gg = (lane << 2) + found;
    }
    const int g1  = __builtin_amdgcn_readlane(gg,  src);
    const int nb1 = __builtin_amdgcn_readlane(nnb, src);

    // ---- masks from bin bytes (bfe + cmp; no floats) ----
    unsigned int maskA = 0u, maskB = 0u;
    #pragma unroll
    for (int j = 0; j < 32; ++j) {
        const int bb = (int)((bp[j >> 2] >> ((j & 3) * 8)) & 255u);
        if (bb < g1) maskA |= (1u << j);
        else if (bb == g1) maskB |= (1u << j);
    }
    maskB &= nearmask;                     // drop far/self sentinels (bin 255)

    const int packed = __popc(maskA) | (__popc(maskB) << 16);
    const int incl2  = wave_incl_scan(packed);
    const int excl2  = incl2 - packed;
    int baseA = excl2 & 0xFFFF;            // region A: [0, nb1)
    int baseB = nb1 + (excl2 >> 16);       // region B: [nb1, 40), capped
    #pragma unroll
    for (int j = 0; j < 32; ++j) {
        const bool a = (maskA >> j) & 1u;
        const bool b = (maskB >> j) & 1u;
        const int  dst = a ? baseA : baseB;
        if ((a | b) && (a || baseB < KNB))
            cp[dst] = lane + (j << 6);
        baseA += (int)a;
        baseB += (int)b;
    }
    return true;
}

// rebuild_fb: rare fallback — re-derive d2, bins at [0,1024) width 4, re-hist.
static __device__ __forceinline__ void rebuild_fb(
    const float4* __restrict__ cb4, const float4 cv, const int jself,
    const int lself, int* __restrict__ hw, unsigned int (&bp)[8],
    unsigned int& nearm, const int lane)
{
    const int4 izero = {0, 0, 0, 0};
    ((int4*)hw)[lane] = izero;
    nearm = 0u;
    #pragma unroll
    for (int q = 0; q < 8; ++q) bp[q] = 0u;
    #pragma unroll
    for (int j = 0; j < 32; ++j) {
        const float4 cw = cb4[lane + (j << 6)];
        const float dx = cv.x - cw.x, dy = cv.y - cw.y;
        const float dz = cv.z - cw.z, dw = cv.w - cw.w;
        float d2 = dx*dx + dy*dy + dz*dz + dw*dw;
        if (j == jself && lane == lself) d2 = FLT_MAX;
        const bool nr = (d2 < 1024.f);
        const int  bb = nr ? (int)(d2 * 0.25f) : 255;
        bp[j >> 2] |= (unsigned int)bb << ((j & 3) * 8);
        nearm      |= (nr ? 1u : 0u) << j;
        if (nr) atomicAdd(&hw[bb], 1);
    }
}

// ---------------------------------------------------------------------------
// Kernel 2a: k_select — top-40 KNN selection, TWO rows per wave, bin-packed.
// R7: R6 spilled the d2 arrays to scratch (VGPR=64, WRITE_SIZE 2x) and
// occupancy pinned at 42%. Fix: drop the float d2 arrays entirely — keep
// 8-bit bin indices (8 u32/row) + nearmask. Collect compares bins vs g1
// (exactly equivalent, see select_collect). The exp(-10*d2) weight moves to
// k_pool (recomputed from coords, full fp32). Per-row state 32->10 VGPRs:
// no spill, high residency. Output: 40 u32 neighbor indices per row into
// the row's `collected` slot (consumed then overwritten by k_pool).
// ---------------------------------------------------------------------------
__global__ __launch_bounds__(256) void k_select(
    const float* __restrict__ coords, float* __restrict__ collected)
{
    __shared__ int hist[4][2][256];    // 8 KB  (per-wave x 2 rows)
    __shared__ int candP[4][2][KNB];   // 1.25 KB: neighbor idx

    const int tid   = threadIdx.x;
    const int lane  = tid & 63;
    const int w     = tid >> 6;
    // XCD swizzle: 8192 blocks, 8 XCDs -> 1024 contiguous blocks per XCD.
    const int bid   = (int)blockIdx.x;
    const int swz   = ((bid & 7) << 10) + (bid >> 3);
    const int batch = swz >> 8;            // 256 blocks of 8 rows per batch
    const int chunk = swz & 255;
    const float4* cb4 = (const float4*)(coords + (size_t)batch * VV * DD);

    const int4 izero = {0, 0, 0, 0};

    // two rows per wave: vA even, vB = vA+1 (both wave-uniform)
    const int vA = __builtin_amdgcn_readfirstlane((chunk << 3) + (w << 1));
    const int vB = vA + 1;
    const float4 cvA = cb4[vA];            // uniform -> scalar loads
    const float4 cvB = cb4[vB];
    const int jself  = vA >> 6;            // == vB >> 6 (vA even)
    const int lselfA = vA & 63;
    const int lselfB = lselfA + 1;

    ((int4*)hist[w][0])[lane] = izero;
    ((int4*)hist[w][1])[lane] = izero;

    // ---- fused distance + bin-pack + histogram for BOTH rows ----
    unsigned int bpA[8] = {0,0,0,0,0,0,0,0};
    unsigned int bpB[8] = {0,0,0,0,0,0,0,0};
    unsigned int nearA = 0u, nearB = 0u;
    #pragma unroll
    for (int j = 0; j < 32; ++j) {
        const float4 cw = cb4[lane + (j << 6)];
        const float dxA = cvA.x - cw.x, dyA = cvA.y - cw.y;
        const float dzA = cvA.z - cw.z, dwA = cvA.w - cw.w;
        float d2A = dxA*dxA + dyA*dyA + dzA*dzA + dwA*dwA;
        const float dxB = cvB.x - cw.x, dyB = cvB.y - cw.y;
        const float dzB = cvB.z - cw.z, dwB = cvB.w - cw.w;
        float d2B = dxB*dxB + dyB*dyB + dzB*dzB + dwB*dwB;
        if (j == jself) {                  // uniform scalar branch
            if (lane == lselfA) d2A = FLT_MAX;
            if (lane == lselfB) d2B = FLT_MAX;
        }
        const bool nA = (d2A < 4.f), nB = (d2B < 4.f);
        const int  bA = nA ? (int)(d2A * 64.f) : 255;
        const int  bB = nB ? (int)(d2B * 64.f) : 255;
        bpA[j >> 2] |= (unsigned int)bA << ((j & 3) * 8);
        bpB[j >> 2] |= (unsigned int)bB << ((j & 3) * 8);
        nearA |= (nA ? 1u : 0u) << j;
        nearB |= (nB ? 1u : 0u) << j;
        if (nA) atomicAdd(&hist[w][0][bA], 1);
        if (nB) atomicAdd(&hist[w][1][bB], 1);
    }

    // ---- per-row select + collect (fallback rare, wave-uniform) ----
    if (!select_collect(bpA, nearA, hist[w][0], candP[w][0], lane, true)) {
        rebuild_fb(cb4, cvA, jself, lselfA, hist[w][0], bpA, nearA, lane);
        select_collect(bpA, nearA, hist[w][0], candP[w][0], lane, false);
    }
    if (!select_collect(bpB, nearB, hist[w][1], candP[w][1], lane, true)) {
        rebuild_fb(cb4, cvB, jself, lselfB, hist[w][1], bpB, nearB, lane);
        select_collect(bpB, nearB, hist[w][1], candP[w][1], lane, false);
    }

    // ---- lanes 0..39: coalesced idx write to both row slots ----
    if (lane < KNB) {
        const unsigned int u0 = (unsigned int)candP[w][0][lane];
        const unsigned int u1 = (unsigned int)candP[w][1][lane];
        unsigned int* rowpA =
            (unsigned int*)(collected + ((size_t)(batch * VV + vA) << 7));
        rowpA[lane]       = u0;
        rowpA[128 + lane] = u1;            // row vB = vA+1: +128 floats
    }
}

// ---------------------------------------------------------------------------
// Kernel 2b: k_pool — gather 40 neighbor feature rows, weighted max/mean.
// R7: weight exp(-10*d2) recomputed here (lanes 0..39, one coords gather +
// 9 VALU + 1 exp per wave) — removes the 12-bit weight pack AND the d2
// state from k_select. Pool loop unchanged: readlane -> SGPR idx/weight,
// saddr gathers, then the row slot is overwritten with the pooled output.
// ---------------------------------------------------------------------------
__global__ __launch_bounds__(256) void k_pool(
    const float* __restrict__ coords, const float* __restrict__ feats,
    float* __restrict__ collected)
{
    const int tid  = threadIdx.x;
    const int lane = tid & 63;
    const int w4   = tid >> 6;             // wave in block: 0..3
    // XCD swizzle: 16384 blocks, 8 XCDs -> 2048 contiguous blocks per XCD.
    const int bid  = (int)blockIdx.x;
    const int swz  = ((bid & 7) << 11) + (bid >> 3);
    const int v    = (swz << 2) + w4;      // global row
    const int batch = v >> 11;
    const float*  fb  = feats + (size_t)batch * VV * PP;
    const float4* cb4 = (const float4*)(coords + (size_t)batch * VV * DD);
    float* rowp = collected + ((size_t)v << 7);

    // packed candidates + per-lane weight (lanes 0..39), before overwrite
    unsigned int u = 0u; float wgt = 0.f;
    if (lane < KNB) {
        u = ((const unsigned int*)rowp)[lane];
        const float4 cv = cb4[v & (VV - 1)];
        const float4 cw = cb4[u];
        const float dx = cv.x - cw.x, dy = cv.y - cw.y;
        const float dz = cv.z - cw.z, dw = cv.w - cw.w;
        wgt = __expf(-10.f * (dx*dx + dy*dy + dz*dz + dw*dw));
    }

    float mx = -FLT_MAX, sm = 0.f;
    #pragma unroll
    for (int j0 = 0; j0 < KNB; j0 += 20) {
        float fv[20]; float wv[20];
        #pragma unroll
        for (int t = 0; t < 20; ++t) {
            const int si = __builtin_amdgcn_readlane((int)u, j0 + t);   // SGPR
            wv[t] = __uint_as_float(
                (unsigned int)__builtin_amdgcn_readlane(__float_as_int(wgt), j0 + t));
            fv[t] = fb[(size_t)(si * PP) + lane];                       // saddr
        }
        #pragma unroll
        for (int t = 0; t < 20; ++t) {
            const float nv = fv[t] * wv[t];
            mx = fmaxf(mx, nv);
            sm += nv;
        }
    }
    rowp[lane]      = mx;
    rowp[PP + lane] = sm * (1.f / KNB);
}

// ---------------------------------------------------------------------------
// Kernel 3: out = tanh(concat(x, collected) @ W_out + b_out), (N x 192)@(192 x 128)
// (unchanged, passing)
// ---------------------------------------------------------------------------
__global__ __launch_bounds__(256) void k_out(
    const float* __restrict__ x, const float* __restrict__ collected,
    const float* __restrict__ Wout, const float* __restrict__ bout,
    float* __restrict__ out)
{
    __shared__ float As[16][68];   // [kk][r], +4 pad
    __shared__ float Bs[16][128];
    const int tid = threadIdx.x;
    const int tx  = tid & 15;
    const int ty  = tid >> 4;
    const int row0 = blockIdx.x * 64;

    float acc[4][8];
    #pragma unroll
    for (int i = 0; i < 4; ++i)
        #pragma unroll
        for (int j = 0; j < 8; ++j) acc[i][j] = 0.f;

    for (int k0 = 0; k0 < 192; k0 += 16) {
        {   // stage A tile transposed: thread loads (r, kk4..kk4+3), scatters
            const int r   = tid >> 2;
            const int kk4 = (tid & 3) << 2;
            const float* src = (k0 < 64)
                ? (x + (size_t)(row0 + r) * FIN + (k0 + kk4))
                : (collected + (size_t)(row0 + r) * 128 + (k0 - 64 + kk4));
            float4 v = *(const float4*)src;
            As[kk4+0][r] = v.x; As[kk4+1][r] = v.y;
            As[kk4+2][r] = v.z; As[kk4+3][r] = v.w;
        }
        #pragma unroll
        for (int rep = 0; rep < 2; ++rep) {
            const int e = (tid + rep * 256) * 4;
            const int kk = e >> 7, c = e & 127;
            *(float4*)&Bs[kk][c] = *(const float4*)(Wout + (size_t)(k0 + kk) * 128 + c);
        }
        __syncthreads();
        #pragma unroll
        for (int kk = 0; kk < 16; ++kk) {
            float4 a  = *(const float4*)&As[kk][ty * 4];
            float4 b0 = *(const float4*)&Bs[kk][tx * 4];
            float4 b1 = *(const float4*)&Bs[kk][64 + tx * 4];
            const float av[4] = {a.x, a.y, a.z, a.w};
            #pragma unroll
            for (int i = 0; i < 4; ++i) {
                acc[i][0] += av[i] * b0.x; acc[i][1] += av[i] * b0.y;
                acc[i][2] += av[i] * b0.z; acc[i][3] += av[i] * b0.w;
                acc[i][4] += av[i] * b1.x; acc[i][5] += av[i] * b1.y;
                acc[i][6] += av[i] * b1.z; acc[i][7] += av[i] * b1.w;
            }
        }
        __syncthreads();
    }

    #pragma unroll
    for (int i = 0; i < 4; ++i) {
        const int row = row0 + ty * 4 + i;
        float4 o0, o1;
        o0.x = fast_tanh(acc[i][0] + bout[tx*4+0]);
        o0.y = fast_tanh(acc[i][1] + bout[tx*4+1]);
        o0.z = fast_tanh(acc[i][2] + bout[tx*4+2]);
        o0.w = fast_tanh(acc[i][3] + bout[tx*4+3]);
        o1.x = fast_tanh(acc[i][4] + bout[64+tx*4+0]);
        o1.y = fast_tanh(acc[i][5] + bout[64+tx*4+1]);
        o1.z = fast_tanh(acc[i][6] + bout[64+tx*4+2]);
        o1.w = fast_tanh(acc[i][7] + bout[64+tx*4+3]);
        *(float4*)(out + (size_t)row * 128 + tx * 4)      = o0;
        *(float4*)(out + (size_t)row * 128 + 64 + tx * 4) = o1;
    }
}

// ---------------------------------------------------------------------------
extern "C" void kernel_launch(void* const* d_in, const int* in_sizes, int n_in,
                              void* d_out, int out_size, void* d_ws, size_t ws_size,
                              hipStream_t stream)
{
    const float* x    = (const float*)d_in[0];
    // d_in[1] = row_splits: uniform arange(B+1)*V — fixed structure, unused.
    const float* Ws   = (const float*)d_in[2];
    const float* bs   = (const float*)d_in[3];
    const float* Wf   = (const float*)d_in[4];
    const float* bf   = (const float*)d_in[5];
    const float* Wout = (const float*)d_in[6];
    const float* bout = (const float*)d_in[7];
    float* out = (float*)d_out;

    float* coords = (float*)d_ws;                                            // 1 MB
    float* feats  = (float*)((char*)d_ws + (size_t)NN * DD * sizeof(float)); // 16 MB
    float* collected = out;   // reuse d_out as scratch for pooled features

    hipLaunchKernelGGL(k_embed, dim3(NN / 64), dim3(256), 0, stream,
                       x, Ws, bs, Wf, bf, coords, feats);
    // selection: 8 rows per block (4 waves x 2 rows) -> 8192 blocks
    hipLaunchKernelGGL(k_select, dim3(NN / 8), dim3(256), 0, stream,
                       coords, collected);
    // pooling: 1 row per wave, 4 waves/block -> 16384 blocks
    hipLaunchKernelGGL(k_pool, dim3(NN / 4), dim3(256), 0, stream,
                       coords, feats, collected);
    hipLaunchKernelGGL(k_out, dim3(NN / 64), dim3(256), 0, stream,
                       x, collected, Wout, bout, out);
}